// Round 20
// baseline (458.793 us; speedup 1.0000x reference)
//
#include <hip/hip_runtime.h>
#include <cstdint>
#include <cstddef>

#define D_DIM 2048
#define D_HID 8192
#define N_TOK 8192

typedef int v4i __attribute__((ext_vector_type(4)));
typedef float v4f __attribute__((ext_vector_type(4)));
typedef _Float16 v8h __attribute__((ext_vector_type(8)));

__device__ __forceinline__ void gload16(const void* g, void* l) {
  __builtin_amdgcn_global_load_lds(
      (__attribute__((address_space(1))) void*)(void*)(const_cast<void*>(g)),
      (__attribute__((address_space(3))) void*)(void*)(l), 16, 0, 0);
}

__device__ __forceinline__ unsigned pack4i8(int a, int b, int c, int d) {
  return (unsigned)(a & 255) | ((unsigned)(b & 255) << 8) |
         ((unsigned)(c & 255) << 16) | ((unsigned)(d & 255) << 24);
}

__device__ __forceinline__ int clampi(int v, int lo, int hi) {
  return v < lo ? lo : (v > hi ? hi : v);
}

// Branch-free exact-GELU via Abramowitz-Stegun 7.1.26 erf (|eps| <= 1.5e-7 abs).
__device__ __forceinline__ float gelu_fast(float c) {
  const float ax = fabsf(c) * 0.70710678118654752440f;
  const float t = 1.0f / fmaf(0.3275911f, ax, 1.0f);
  const float poly =
      t * fmaf(t, fmaf(t, fmaf(t, fmaf(t, 1.061405429f, -1.453152027f),
                               1.421413741f), -0.284496736f), 0.254829592f);
  const float e = 1.0f - poly * __expf(-ax * ax);
  const float es = copysignf(e, c);
  return 0.5f * c * (1.0f + es);
}

// ---------------- weight |w| sum (fixed-order f64, deterministic) ------------
__global__ __launch_bounds__(256) void wsum_k(const float* __restrict__ w1,
                                              const float* __restrict__ w2,
                                              double* __restrict__ part) {
  const int b = blockIdx.x;
  const float* w = (b < 1024) ? w1 : w2;
  const size_t base = (size_t)(b & 1023) * 16384;
  const int t = threadIdx.x;
  double s = 0.0;
  for (int i = 0; i < 64; ++i) s += fabs((double)w[base + (size_t)i * 256 + t]);
  __shared__ double red[256];
  red[t] = s;
  __syncthreads();
  for (int st = 128; st; st >>= 1) {
    if (t < st) red[t] += red[t + st];
    __syncthreads();
  }
  if (!t) part[b] = red[0];
}

__global__ __launch_bounds__(256) void wfinal_k(const double* __restrict__ part,
                                                double* __restrict__ swd,
                                                float* __restrict__ wsc) {
  __shared__ double red[256];
  const int t = threadIdx.x;
  for (int m = 0; m < 2; ++m) {
    double s = part[m * 1024 + t] + part[m * 1024 + 256 + t] +
               part[m * 1024 + 512 + t] + part[m * 1024 + 768 + t];
    red[t] = s;
    __syncthreads();
    for (int st = 128; st; st >>= 1) {
      if (t < st) red[t] += red[t + st];
      __syncthreads();
    }
    if (!t) {
      double mean = red[0] / 16777216.0;
      double m2 = fmax(mean, 1e-5);
      swd[m] = 1.0 / m2;
      wsc[m] = (float)m2;
    }
    __syncthreads();
  }
}

// ---------------- ternary weight quant (f64 decision, half-even) -------------
__global__ __launch_bounds__(256) void wquant_k(const float* __restrict__ w,
                                                int8_t* __restrict__ q,
                                                const double* __restrict__ swd, int idx) {
  const double s = swd[idx];
  const size_t i = ((size_t)blockIdx.x * 256 + threadIdx.x) * 4;
  const float4 v = *(const float4*)&w[i];
  const int q0 = clampi((int)__builtin_rint((double)v.x * s), -1, 1);
  const int q1 = clampi((int)__builtin_rint((double)v.y * s), -1, 1);
  const int q2 = clampi((int)__builtin_rint((double)v.z * s), -1, 1);
  const int q3 = clampi((int)__builtin_rint((double)v.w * s), -1, 1);
  *(unsigned*)&q[i] = pack4i8(q0, q1, q2, q3);
}

// ---------------- fused RMSNorm + per-token absmax int8 quant ----------------
__global__ __launch_bounds__(256) void rmsq_k(const float* __restrict__ x,
                                              const float* __restrict__ gamma,
                                              int8_t* __restrict__ qx,
                                              float* __restrict__ sxinv) {
  const int row = blockIdx.x, t = threadIdx.x;
  const float* xr = x + (size_t)row * D_DIM;
  const v4f v0 = __builtin_nontemporal_load((const v4f*)&xr[t * 4]);
  const v4f v1 = __builtin_nontemporal_load((const v4f*)&xr[1024 + t * 4]);
  double xs[8] = {v0[0], v0[1], v0[2], v0[3], v1[0], v1[1], v1[2], v1[3]};
  double ssq = 0.0;
#pragma unroll
  for (int j = 0; j < 8; ++j) ssq += xs[j] * xs[j];
  __shared__ double red[256];
  red[t] = ssq;
  __syncthreads();
  for (int st = 128; st; st >>= 1) {
    if (t < st) red[t] += red[t + st];
    __syncthreads();
  }
  const double rn = 1.0 / sqrt(red[0] / (double)D_DIM + 1e-6);
  __syncthreads();
  const float4 g0 = *(const float4*)&gamma[t * 4];
  const float4 g1 = *(const float4*)&gamma[1024 + t * 4];
  const double gs[8] = {g0.x, g0.y, g0.z, g0.w, g1.x, g1.y, g1.z, g1.w};
  double xn[8], am = 0.0;
#pragma unroll
  for (int j = 0; j < 8; ++j) {
    xn[j] = xs[j] * rn * gs[j];
    am = fmax(am, fabs(xn[j]));
  }
  red[t] = am;
  __syncthreads();
  for (int st = 128; st; st >>= 1) {
    if (t < st) red[t] = fmax(red[t], red[t + st]);
    __syncthreads();
  }
  const double amax = fmax(red[0], 1e-5);
  const double s = 127.0 / amax;
  int q[8];
#pragma unroll
  for (int j = 0; j < 8; ++j) q[j] = clampi((int)__builtin_rint(xn[j] * s), -128, 127);
  unsigned* qo = (unsigned*)(qx + (size_t)row * D_DIM);
  qo[t] = pack4i8(q[0], q[1], q[2], q[3]);
  qo[256 + t] = pack4i8(q[4], q[5], q[6], q[7]);
  if (!t) sxinv[row] = (float)(amax / 127.0);
}

// ------- fused gelu + per-token absmax + int8 quant of f16 h (path A16) ------
__global__ __launch_bounds__(256) void hgeluq_k(const _Float16* __restrict__ h16,
                                                int8_t* __restrict__ qh,
                                                float* __restrict__ shinv) {
  const int row = blockIdx.x, t = threadIdx.x;
  const _Float16* hr = h16 + (size_t)row * D_HID;
  float gv[32];
  float am = 0.f;
#pragma unroll
  for (int j = 0; j < 4; ++j) {
    const v8h v = __builtin_nontemporal_load((const v8h*)&hr[j * 2048 + t * 8]);
#pragma unroll
    for (int e = 0; e < 8; ++e) {
      const float g = gelu_fast((float)v[e]);
      gv[j * 8 + e] = g;
      am = fmaxf(am, fabsf(g));
    }
  }
  __shared__ float red[256];
  red[t] = am;
  __syncthreads();
  for (int st = 128; st; st >>= 1) {
    if (t < st) red[t] = fmaxf(red[t], red[t + st]);
    __syncthreads();
  }
  const double amax = fmax((double)red[0], 1e-5);
  const double s = 127.0 / amax;
  if (!t) shinv[row] = (float)(amax / 127.0);
  unsigned* qo = (unsigned*)(qh + (size_t)row * D_HID);
#pragma unroll
  for (int j = 0; j < 4; ++j) {
    int q[8];
#pragma unroll
    for (int e = 0; e < 8; ++e)
      q[e] = clampi((int)__builtin_rint((double)gv[j * 8 + e] * s), -128, 127);
    qo[j * 512 + t * 2 + 0] = pack4i8(q[0], q[1], q[2], q[3]);
    qo[j * 512 + t * 2 + 1] = pack4i8(q[4], q[5], q[6], q[7]);
  }
}

// ==== int8 NT GEMM, 128x128, BK=64, dbuf, 2-WAVE blocks (64x128 per wave) ====
// R19 audit: LDS port ~69% busy = dominant pipe. 2x2-wave geometry reads every
// subblock twice (32 KiB reads/tile). This 2-wave geometry (wave w owns rows
// [64w,64w+64) x ALL cols): reads = 2x(4 A + 8 B) = 24 KiB/tile -> LDS/tile
// 48->40 KiB, port floor 123->103 us/GEMM. acc[4][8] = 128 AGPR + ~65 VGPR
// < 256-reg cap at __launch_bounds__(128,2) (no spill; R14 arithmetic). Same
// verified conflict-free subblock layout, staging source permutation,
// super-column XCD-contiguous order, issue-early/wait-late schedule.
// Tradeoff: 8 waves/CU (2/SIMD) instead of 16 — port relief vs TLP.
// EPI: 0 gelu rowmax (fallback); 2 dequant nt-store; 3 gelu + i8 quant store
//      (fallback); 5 raw-h f16 nt-store (path A16).
template <int EPI>
__global__ __launch_bounds__(128, 2) void gemm2w_i8_k(const int8_t* __restrict__ A,
                                                      const int8_t* __restrict__ B, int K,
                                                      int NB_X,
                                                      float* __restrict__ Cf,
                                                      _Float16* __restrict__ Ch,
                                                      int8_t* __restrict__ Cq, int ldc,
                                                      const float* __restrict__ rowf,
                                                      const float* __restrict__ wscp,
                                                      unsigned* __restrict__ amax) {
  __shared__ __align__(16) int8_t Al[2][8192];
  __shared__ __align__(16) int8_t Bl[2][8192];
  const int tid = threadIdx.x;
  const int wave = tid >> 6, lane = tid & 63;  // 2 waves
  const int hi = lane >> 4, lo = lane & 15;

  const int nwg = gridDim.x;  // multiple of 8; super-columns of 8 col-panels
  const int bid = blockIdx.x;
  const int lid = (bid & 7) * (nwg >> 3) + (bid >> 3);  // XCD-contiguous
  const int grp = lid >> 9;
  const int rem = lid & 511;
  const int by = rem >> 3;
  const int bx = (grp << 3) | (rem & 7);
  const int row0 = by * 128, col0 = bx * 128;

  // staging source: row (lane>>2), kchunk (lane&3)^((lane>>3)&3); wave w
  // stages subblocks 4w..4w+3 of both A and B (8 gloads/tile/wave).
  const int srow = lane >> 2;
  const int skb = ((lane & 3) ^ ((lane >> 3) & 3)) * 16;
  size_t aG[4], bG[4];
#pragma unroll
  for (int i = 0; i < 4; ++i) {
    const int mb = 4 * wave + i;
    aG[i] = (size_t)(row0 + mb * 16 + srow) * K + skb;
    bG[i] = (size_t)(col0 + mb * 16 + srow) * K + skb;
  }
  const int lsb = 4 * wave * 1024;
  const int NT = K >> 6;

  v4i acc[4][8];
#pragma unroll
  for (int m = 0; m < 4; ++m)
#pragma unroll
    for (int n = 0; n < 8; ++n) acc[m][n] = (v4i){0, 0, 0, 0};

  const int roff = lo * 64 + ((hi ^ ((lo >> 1) & 3)) * 16);
  const int asb = 4 * wave;  // wave's A subblocks (its 64 rows)

#define STG(buf, T)                                                            \
  do {                                                                         \
    const size_t ko_ = (size_t)(T) * 64;                                       \
    gload16(A + aG[0] + ko_, &Al[buf][lsb]);                                   \
    gload16(A + aG[1] + ko_, &Al[buf][lsb + 1024]);                            \
    gload16(A + aG[2] + ko_, &Al[buf][lsb + 2048]);                            \
    gload16(A + aG[3] + ko_, &Al[buf][lsb + 3072]);                            \
    gload16(B + bG[0] + ko_, &Bl[buf][lsb]);                                   \
    gload16(B + bG[1] + ko_, &Bl[buf][lsb + 1024]);                            \
    gload16(B + bG[2] + ko_, &Bl[buf][lsb + 2048]);                            \
    gload16(B + bG[3] + ko_, &Bl[buf][lsb + 3072]);                            \
  } while (0)

  // prologue
  STG(0, 0);
  asm volatile("s_waitcnt vmcnt(0)" ::: "memory");
  __syncthreads();

  int buf = 0;
#pragma unroll 1
  for (int t = 0; t < NT; ++t) {
    if (t + 1 < NT) STG(buf ^ 1, t + 1);  // issue-early
    v4i af[4], bf[8];
#pragma unroll
    for (int m = 0; m < 4; ++m) af[m] = *(const v4i*)&Al[buf][(asb + m) * 1024 + roff];
#pragma unroll
    for (int n = 0; n < 8; ++n) bf[n] = *(const v4i*)&Bl[buf][n * 1024 + roff];
    __builtin_amdgcn_s_setprio(1);
#pragma unroll
    for (int m = 0; m < 4; ++m)
#pragma unroll
      for (int n = 0; n < 8; ++n)
        acc[m][n] = __builtin_amdgcn_mfma_i32_16x16x64_i8(af[m], bf[n], acc[m][n], 0, 0, 0);
    __builtin_amdgcn_s_setprio(0);
    asm volatile("s_waitcnt vmcnt(0)" ::: "memory");  // wait-late (absorbed)
    __syncthreads();
    buf ^= 1;
  }
#undef STG

  // ---- epilogue ----
  const float mw = wscp[0];
#pragma unroll
  for (int m = 0; m < 4; ++m) {
#pragma unroll
    for (int r = 0; r < 4; ++r) {
      const int grow = row0 + wave * 64 + m * 16 + hi * 4 + r;
      const float f = rowf[grow] * mw;
      if constexpr (EPI == 5) {
#pragma unroll
        for (int n = 0; n < 8; ++n) {
          const int gcol = col0 + n * 16 + lo;
          __builtin_nontemporal_store((_Float16)((float)acc[m][n][r] * f),
                                      &Ch[(size_t)grow * ldc + gcol]);
        }
      } else if constexpr (EPI == 0) {
        float rmax = 0.f;
#pragma unroll
        for (int n = 0; n < 8; ++n) {
          const float c = (float)acc[m][n][r] * f;
          rmax = fmaxf(rmax, fabsf(gelu_fast(c)));
        }
#pragma unroll
        for (int sh = 1; sh < 16; sh <<= 1) rmax = fmaxf(rmax, __shfl_xor(rmax, sh));
        if (lo == 0) atomicMax(&amax[grow], __float_as_uint(rmax));
      } else if constexpr (EPI == 3) {
        const double s = 127.0 / fmax((double)__uint_as_float(amax[grow]), 1e-5);
#pragma unroll
        for (int n = 0; n < 8; ++n) {
          const int gcol = col0 + n * 16 + lo;
          const float c = (float)acc[m][n][r] * f;
          const float gv = gelu_fast(c);
          Cq[(size_t)grow * ldc + gcol] =
              (int8_t)clampi((int)__builtin_rint((double)gv * s), -128, 127);
        }
      } else {
#pragma unroll
        for (int n = 0; n < 8; ++n) {
          const int gcol = col0 + n * 16 + lo;
          __builtin_nontemporal_store((float)acc[m][n][r] * f,
                                      &Cf[(size_t)grow * ldc + gcol]);
        }
      }
    }
  }
}

__global__ void fill_k(float* p, int n, float v) {
  int i = blockIdx.x * 256 + threadIdx.x;
  if (i < n) p[i] = v;
}

__global__ __launch_bounds__(256) void scalefix_k(const unsigned* __restrict__ amaxh,
                                                  float* __restrict__ shinv) {
  const int i = blockIdx.x * 256 + threadIdx.x;
  if (i < N_TOK)
    shinv[i] = (float)(fmax((double)__uint_as_float(amaxh[i]), 1e-5) / 127.0);
}

extern "C" void kernel_launch(void* const* d_in, const int* in_sizes, int n_in, void* d_out,
                              int out_size, void* d_ws, size_t ws_size, hipStream_t stream) {
  const float* x = (const float*)d_in[0];
  const float* w1 = (const float*)d_in[1];
  const float* w2 = (const float*)d_in[2];
  const float* gamma = (const float*)d_in[3];
  float* out = (float*)d_out;
  char* ws = (char*)d_ws;

  const size_t SQX = (size_t)N_TOK * D_DIM;
  const size_t SQW1 = (size_t)D_HID * D_DIM;
  const size_t SQW2 = (size_t)D_DIM * D_HID;
  const size_t SQH = (size_t)N_TOK * D_HID;
  const size_t SG16 = (size_t)N_TOK * D_HID * 2;  // 128 MiB f16 h

  size_t off = 0;
  int8_t* qx = (int8_t*)(ws + off);  off += SQX;
  int8_t* qw1 = (int8_t*)(ws + off); off += SQW1;
  int8_t* qw2 = (int8_t*)(ws + off); off += SQW2;
  int8_t* qh = (int8_t*)(ws + off);  off += SQH;
  float* sxinv = (float*)(ws + off);       off += (size_t)N_TOK * 4;
  unsigned* amaxh = (unsigned*)(ws + off); off += (size_t)N_TOK * 4;
  float* shinv = (float*)(ws + off);       off += (size_t)N_TOK * 4;
  double* wpart = (double*)(ws + off);     off += 2048 * 8;
  double* swd = (double*)(ws + off);       off += 2 * 8;
  float* wsc = (float*)(ws + off);         off += 2 * 4;
  off = (off + 255) & ~(size_t)255;
  const size_t needB = off;
  _Float16* h16 = (_Float16*)(ws + off);
  const size_t needA16 = off + SG16;

  if (ws_size < needB) {
    const float v = 100000.0f + (float)(ws_size >> 20);
    fill_k<<<(out_size + 255) / 256, 256, 0, stream>>>(out, out_size, v);
    return;
  }
  const bool pathA16 = (ws_size >= needA16);

  wsum_k<<<2048, 256, 0, stream>>>(w1, w2, wpart);
  wfinal_k<<<1, 256, 0, stream>>>(wpart, swd, wsc);
  wquant_k<<<16384, 256, 0, stream>>>(w1, qw1, swd, 0);
  wquant_k<<<16384, 256, 0, stream>>>(w2, qw2, swd, 1);
  rmsq_k<<<N_TOK, 256, 0, stream>>>(x, gamma, qx, sxinv);

  const int nwg1 = (N_TOK / 128) * (D_HID / 128);  // 4096
  const int nwg2 = (N_TOK / 128) * (D_DIM / 128);  // 1024
  if (pathA16) {
    gemm2w_i8_k<5><<<nwg1, 128, 0, stream>>>(qx, qw1, D_DIM, D_HID / 128, nullptr, h16,
                                             nullptr, D_HID, sxinv, wsc + 0, nullptr);
    hgeluq_k<<<N_TOK, 256, 0, stream>>>(h16, qh, shinv);
  } else {
    hipMemsetAsync(amaxh, 0, (size_t)N_TOK * 4, stream);
    gemm2w_i8_k<0><<<nwg1, 128, 0, stream>>>(qx, qw1, D_DIM, D_HID / 128, nullptr, nullptr,
                                             nullptr, D_HID, sxinv, wsc + 0, amaxh);
    scalefix_k<<<(N_TOK + 255) / 256, 256, 0, stream>>>(amaxh, shinv);
    gemm2w_i8_k<3><<<nwg1, 128, 0, stream>>>(qx, qw1, D_DIM, D_HID / 128, nullptr, nullptr,
                                             qh, D_HID, sxinv, wsc + 0, amaxh);
  }
  gemm2w_i8_k<2><<<nwg2, 128, 0, stream>>>(qh, qw2, D_HID, D_DIM / 128, out, nullptr,
                                           nullptr, D_DIM, shinv, wsc + 1, nullptr);
}

// Round 21
// 447.577 us; speedup vs baseline: 1.0251x; 1.0251x over previous
//
#include <hip/hip_runtime.h>
#include <cstdint>
#include <cstddef>

#define D_DIM 2048
#define D_HID 8192
#define N_TOK 8192

typedef int v4i __attribute__((ext_vector_type(4)));
typedef float v4f __attribute__((ext_vector_type(4)));
typedef _Float16 v8h __attribute__((ext_vector_type(8)));

__device__ __forceinline__ void gload16(const void* g, void* l) {
  __builtin_amdgcn_global_load_lds(
      (__attribute__((address_space(1))) void*)(void*)(const_cast<void*>(g)),
      (__attribute__((address_space(3))) void*)(void*)(l), 16, 0, 0);
}

__device__ __forceinline__ unsigned pack4i8(int a, int b, int c, int d) {
  return (unsigned)(a & 255) | ((unsigned)(b & 255) << 8) |
         ((unsigned)(c & 255) << 16) | ((unsigned)(d & 255) << 24);
}

__device__ __forceinline__ int clampi(int v, int lo, int hi) {
  return v < lo ? lo : (v > hi ? hi : v);
}

// Branch-free exact-GELU via Abramowitz-Stegun 7.1.26 erf (|eps| <= 1.5e-7 abs).
__device__ __forceinline__ float gelu_fast(float c) {
  const float ax = fabsf(c) * 0.70710678118654752440f;
  const float t = 1.0f / fmaf(0.3275911f, ax, 1.0f);
  const float poly =
      t * fmaf(t, fmaf(t, fmaf(t, fmaf(t, 1.061405429f, -1.453152027f),
                               1.421413741f), -0.284496736f), 0.254829592f);
  const float e = 1.0f - poly * __expf(-ax * ax);
  const float es = copysignf(e, c);
  return 0.5f * c * (1.0f + es);
}

// ---------------- weight |w| sum (fixed-order f64, deterministic) ------------
__global__ __launch_bounds__(256) void wsum_k(const float* __restrict__ w1,
                                              const float* __restrict__ w2,
                                              double* __restrict__ part) {
  const int b = blockIdx.x;
  const float* w = (b < 1024) ? w1 : w2;
  const size_t base = (size_t)(b & 1023) * 16384;
  const int t = threadIdx.x;
  double s = 0.0;
  for (int i = 0; i < 64; ++i) s += fabs((double)w[base + (size_t)i * 256 + t]);
  __shared__ double red[256];
  red[t] = s;
  __syncthreads();
  for (int st = 128; st; st >>= 1) {
    if (t < st) red[t] += red[t + st];
    __syncthreads();
  }
  if (!t) part[b] = red[0];
}

__global__ __launch_bounds__(256) void wfinal_k(const double* __restrict__ part,
                                                double* __restrict__ swd,
                                                float* __restrict__ wsc) {
  __shared__ double red[256];
  const int t = threadIdx.x;
  for (int m = 0; m < 2; ++m) {
    double s = part[m * 1024 + t] + part[m * 1024 + 256 + t] +
               part[m * 1024 + 512 + t] + part[m * 1024 + 768 + t];
    red[t] = s;
    __syncthreads();
    for (int st = 128; st; st >>= 1) {
      if (t < st) red[t] += red[t + st];
      __syncthreads();
    }
    if (!t) {
      double mean = red[0] / 16777216.0;
      double m2 = fmax(mean, 1e-5);
      swd[m] = 1.0 / m2;
      wsc[m] = (float)m2;
    }
    __syncthreads();
  }
}

// ---------------- ternary weight quant (f64 decision, half-even) -------------
__global__ __launch_bounds__(256) void wquant_k(const float* __restrict__ w,
                                                int8_t* __restrict__ q,
                                                const double* __restrict__ swd, int idx) {
  const double s = swd[idx];
  const size_t i = ((size_t)blockIdx.x * 256 + threadIdx.x) * 4;
  const float4 v = *(const float4*)&w[i];
  const int q0 = clampi((int)__builtin_rint((double)v.x * s), -1, 1);
  const int q1 = clampi((int)__builtin_rint((double)v.y * s), -1, 1);
  const int q2 = clampi((int)__builtin_rint((double)v.z * s), -1, 1);
  const int q3 = clampi((int)__builtin_rint((double)v.w * s), -1, 1);
  *(unsigned*)&q[i] = pack4i8(q0, q1, q2, q3);
}

// ---------------- fused RMSNorm + per-token absmax int8 quant ----------------
__global__ __launch_bounds__(256) void rmsq_k(const float* __restrict__ x,
                                              const float* __restrict__ gamma,
                                              int8_t* __restrict__ qx,
                                              float* __restrict__ sxinv) {
  const int row = blockIdx.x, t = threadIdx.x;
  const float* xr = x + (size_t)row * D_DIM;
  const v4f v0 = __builtin_nontemporal_load((const v4f*)&xr[t * 4]);
  const v4f v1 = __builtin_nontemporal_load((const v4f*)&xr[1024 + t * 4]);
  double xs[8] = {v0[0], v0[1], v0[2], v0[3], v1[0], v1[1], v1[2], v1[3]};
  double ssq = 0.0;
#pragma unroll
  for (int j = 0; j < 8; ++j) ssq += xs[j] * xs[j];
  __shared__ double red[256];
  red[t] = ssq;
  __syncthreads();
  for (int st = 128; st; st >>= 1) {
    if (t < st) red[t] += red[t + st];
    __syncthreads();
  }
  const double rn = 1.0 / sqrt(red[0] / (double)D_DIM + 1e-6);
  __syncthreads();
  const float4 g0 = *(const float4*)&gamma[t * 4];
  const float4 g1 = *(const float4*)&gamma[1024 + t * 4];
  const double gs[8] = {g0.x, g0.y, g0.z, g0.w, g1.x, g1.y, g1.z, g1.w};
  double xn[8], am = 0.0;
#pragma unroll
  for (int j = 0; j < 8; ++j) {
    xn[j] = xs[j] * rn * gs[j];
    am = fmax(am, fabs(xn[j]));
  }
  red[t] = am;
  __syncthreads();
  for (int st = 128; st; st >>= 1) {
    if (t < st) red[t] = fmax(red[t], red[t + st]);
    __syncthreads();
  }
  const double amax = fmax(red[0], 1e-5);
  const double s = 127.0 / amax;
  int q[8];
#pragma unroll
  for (int j = 0; j < 8; ++j) q[j] = clampi((int)__builtin_rint(xn[j] * s), -128, 127);
  unsigned* qo = (unsigned*)(qx + (size_t)row * D_DIM);
  qo[t] = pack4i8(q[0], q[1], q[2], q[3]);
  qo[256 + t] = pack4i8(q[4], q[5], q[6], q[7]);
  if (!t) sxinv[row] = (float)(amax / 127.0);
}

// ------- fused gelu + per-token absmax + int8 quant of f16 h (path A16) ------
// Reads raw f16 h (one full row per block, 32 el/thread in regs), computes
// gelu in f32, block-reduces row absmax (fixed order, no atomics), quantizes.
__global__ __launch_bounds__(256) void hgeluq_k(const _Float16* __restrict__ h16,
                                                int8_t* __restrict__ qh,
                                                float* __restrict__ shinv) {
  const int row = blockIdx.x, t = threadIdx.x;
  const _Float16* hr = h16 + (size_t)row * D_HID;
  float gv[32];
  float am = 0.f;
#pragma unroll
  for (int j = 0; j < 4; ++j) {
    const v8h v = __builtin_nontemporal_load((const v8h*)&hr[j * 2048 + t * 8]);
#pragma unroll
    for (int e = 0; e < 8; ++e) {
      const float g = gelu_fast((float)v[e]);
      gv[j * 8 + e] = g;
      am = fmaxf(am, fabsf(g));
    }
  }
  __shared__ float red[256];
  red[t] = am;
  __syncthreads();
  for (int st = 128; st; st >>= 1) {
    if (t < st) red[t] = fmaxf(red[t], red[t + st]);
    __syncthreads();
  }
  const double amax = fmax((double)red[0], 1e-5);
  const double s = 127.0 / amax;
  if (!t) shinv[row] = (float)(amax / 127.0);
  unsigned* qo = (unsigned*)(qh + (size_t)row * D_HID);
#pragma unroll
  for (int j = 0; j < 4; ++j) {
    int q[8];
#pragma unroll
    for (int e = 0; e < 8; ++e)
      q[e] = clampi((int)__builtin_rint((double)gv[j * 8 + e] * s), -128, 127);
    qo[j * 512 + t * 2 + 0] = pack4i8(q[0], q[1], q[2], q[3]);
    qo[j * 512 + t * 2 + 1] = pack4i8(q[4], q[5], q[6], q[7]);
  }
}

__global__ __launch_bounds__(256) void scalefix_k(const unsigned* __restrict__ amaxh,
                                                  float* __restrict__ shinv) {
  const int i = blockIdx.x * 256 + threadIdx.x;
  if (i < N_TOK)
    shinv[i] = (float)(fmax((double)__uint_as_float(amaxh[i]), 1e-5) / 127.0);
}

// ==== int8 NT GEMM, 128x128, BK=64, dbuf 2-phase, 4 blocks/CU, L2-local ======
// SESSION-BEST VERIFIED (R19: 447.5 us total; GEMM1 174 us MfmaUtil 35.5%,
// GEMM2 145 us, conflicts 0, FETCH ~97 MB, occupancy 42%).
// Closed levers (counter evidence): schedules (R3,R6-R9,R12 neutral/negative);
// occupancy up = acc spill (R14), down = TLP loss (R20 2-wave: 174->192 us);
// 32x32x32 shape bank-conflicted (R16/R17); B-direct latency-exposed (R12);
// heavy epilogue = moved to hgeluq_k (R19 win). 4-wave/4-block is the optimum
// of this structure family.
// EPI: 0 gelu rowmax (fallback); 2 dequant nt-store; 3 gelu + i8 quant store
//      (fallback); 5 raw-h f16 nt-store (path A16).
template <int EPI>
__global__ __launch_bounds__(256, 4) void gemm4_i8_k(const int8_t* __restrict__ A,
                                                     const int8_t* __restrict__ B, int K,
                                                     int NB_X,
                                                     float* __restrict__ Cf,
                                                     _Float16* __restrict__ Ch,
                                                     int8_t* __restrict__ Cq, int ldc,
                                                     const float* __restrict__ rowf,
                                                     const float* __restrict__ wscp,
                                                     unsigned* __restrict__ amax) {
  __shared__ __align__(16) int8_t Al[2][8192];
  __shared__ __align__(16) int8_t Bl[2][8192];
  const int tid = threadIdx.x;
  const int wave = tid >> 6, lane = tid & 63;
  const int hi = lane >> 4, lo = lane & 15;
  const int wr = (wave >> 1) * 64, wc = (wave & 1) * 64;

  const int nwg = gridDim.x;  // multiple of 8; super-columns of 8 col-panels
  const int bid = blockIdx.x;
  const int lid = (bid & 7) * (nwg >> 3) + (bid >> 3);  // XCD-contiguous
  const int grp = lid >> 9;
  const int rem = lid & 511;
  const int by = rem >> 3;
  const int bx = (grp << 3) | (rem & 7);
  const int row0 = by * 128, col0 = bx * 128;

  // staging source: row (lane>>2), kchunk (lane&3)^((lane>>3)&3)
  const int srow = lane >> 2;
  const int skb = ((lane & 3) ^ ((lane >> 3) & 3)) * 16;
  const size_t aG0 = (size_t)(row0 + (2 * wave + 0) * 16 + srow) * K + skb;
  const size_t aG1 = (size_t)(row0 + (2 * wave + 1) * 16 + srow) * K + skb;
  const size_t bG0 = (size_t)(col0 + (2 * wave + 0) * 16 + srow) * K + skb;
  const size_t bG1 = (size_t)(col0 + (2 * wave + 1) * 16 + srow) * K + skb;
  const int ls0 = (2 * wave + 0) * 1024, ls1 = (2 * wave + 1) * 1024;
  const int NT = K >> 6;

  v4i acc[4][4];
#pragma unroll
  for (int m = 0; m < 4; ++m)
#pragma unroll
    for (int n = 0; n < 4; ++n) acc[m][n] = (v4i){0, 0, 0, 0};

  const int roff = lo * 64 + ((hi ^ ((lo >> 1) & 3)) * 16);
  const int asb = (wr >> 4);
  const int bsb = (wc >> 4);

#define STG(buf, T)                                                            \
  do {                                                                         \
    const size_t ko_ = (size_t)(T) * 64;                                       \
    gload16(A + aG0 + ko_, &Al[buf][ls0]);                                     \
    gload16(A + aG1 + ko_, &Al[buf][ls1]);                                     \
    gload16(B + bG0 + ko_, &Bl[buf][ls0]);                                     \
    gload16(B + bG1 + ko_, &Bl[buf][ls1]);                                     \
  } while (0)

  // prologue
  STG(0, 0);
  asm volatile("s_waitcnt vmcnt(0)" ::: "memory");
  __syncthreads();

  int buf = 0;
#pragma unroll 1
  for (int t = 0; t < NT; ++t) {
    if (t + 1 < NT) STG(buf ^ 1, t + 1);  // issue-early
    v4i af[4], bf[4];
#pragma unroll
    for (int m = 0; m < 4; ++m) af[m] = *(const v4i*)&Al[buf][(asb + m) * 1024 + roff];
#pragma unroll
    for (int n = 0; n < 4; ++n) bf[n] = *(const v4i*)&Bl[buf][(bsb + n) * 1024 + roff];
    __builtin_amdgcn_s_setprio(1);
#pragma unroll
    for (int m = 0; m < 4; ++m)
#pragma unroll
      for (int n = 0; n < 4; ++n)
        acc[m][n] = __builtin_amdgcn_mfma_i32_16x16x64_i8(af[m], bf[n], acc[m][n], 0, 0, 0);
    __builtin_amdgcn_s_setprio(0);
    asm volatile("s_waitcnt vmcnt(0)" ::: "memory");  // wait-late (absorbed)
    __syncthreads();
    buf ^= 1;
  }
#undef STG

  // ---- epilogue ----
  const float mw = wscp[0];
#pragma unroll
  for (int m = 0; m < 4; ++m) {
#pragma unroll
    for (int r = 0; r < 4; ++r) {
      const int grow = row0 + wr + m * 16 + hi * 4 + r;
      const float f = rowf[grow] * mw;
      if constexpr (EPI == 5) {
#pragma unroll
        for (int n = 0; n < 4; ++n) {
          const int gcol = col0 + wc + n * 16 + lo;
          __builtin_nontemporal_store((_Float16)((float)acc[m][n][r] * f),
                                      &Ch[(size_t)grow * ldc + gcol]);
        }
      } else if constexpr (EPI == 0) {
        float rmax = 0.f;
#pragma unroll
        for (int n = 0; n < 4; ++n) {
          const int gcol = col0 + wc + n * 16 + lo;
          const float c = (float)acc[m][n][r] * f;
          const float gv = gelu_fast(c);
          rmax = fmaxf(rmax, fabsf(gv));
        }
#pragma unroll
        for (int sh = 1; sh < 16; sh <<= 1) rmax = fmaxf(rmax, __shfl_xor(rmax, sh));
        if (lo == 0) atomicMax(&amax[grow], __float_as_uint(rmax));
      } else if constexpr (EPI == 3) {
        const double s = 127.0 / fmax((double)__uint_as_float(amax[grow]), 1e-5);
#pragma unroll
        for (int n = 0; n < 4; ++n) {
          const int gcol = col0 + wc + n * 16 + lo;
          const float c = (float)acc[m][n][r] * f;
          const float gv = gelu_fast(c);
          Cq[(size_t)grow * ldc + gcol] =
              (int8_t)clampi((int)__builtin_rint((double)gv * s), -128, 127);
        }
      } else {
#pragma unroll
        for (int n = 0; n < 4; ++n) {
          const int gcol = col0 + wc + n * 16 + lo;
          __builtin_nontemporal_store((float)acc[m][n][r] * f,
                                      &Cf[(size_t)grow * ldc + gcol]);
        }
      }
    }
  }
}

__global__ void fill_k(float* p, int n, float v) {
  int i = blockIdx.x * 256 + threadIdx.x;
  if (i < n) p[i] = v;
}

extern "C" void kernel_launch(void* const* d_in, const int* in_sizes, int n_in, void* d_out,
                              int out_size, void* d_ws, size_t ws_size, hipStream_t stream) {
  const float* x = (const float*)d_in[0];
  const float* w1 = (const float*)d_in[1];
  const float* w2 = (const float*)d_in[2];
  const float* gamma = (const float*)d_in[3];
  float* out = (float*)d_out;
  char* ws = (char*)d_ws;

  const size_t SQX = (size_t)N_TOK * D_DIM;
  const size_t SQW1 = (size_t)D_HID * D_DIM;
  const size_t SQW2 = (size_t)D_DIM * D_HID;
  const size_t SQH = (size_t)N_TOK * D_HID;
  const size_t SG16 = (size_t)N_TOK * D_HID * 2;  // 128 MiB f16 h

  size_t off = 0;
  int8_t* qx = (int8_t*)(ws + off);  off += SQX;
  int8_t* qw1 = (int8_t*)(ws + off); off += SQW1;
  int8_t* qw2 = (int8_t*)(ws + off); off += SQW2;
  int8_t* qh = (int8_t*)(ws + off);  off += SQH;
  float* sxinv = (float*)(ws + off);       off += (size_t)N_TOK * 4;
  unsigned* amaxh = (unsigned*)(ws + off); off += (size_t)N_TOK * 4;
  float* shinv = (float*)(ws + off);       off += (size_t)N_TOK * 4;
  double* wpart = (double*)(ws + off);     off += 2048 * 8;
  double* swd = (double*)(ws + off);       off += 2 * 8;
  float* wsc = (float*)(ws + off);         off += 2 * 4;
  off = (off + 255) & ~(size_t)255;
  const size_t needB = off;
  _Float16* h16 = (_Float16*)(ws + off);
  const size_t needA16 = off + SG16;

  if (ws_size < needB) {
    const float v = 100000.0f + (float)(ws_size >> 20);
    fill_k<<<(out_size + 255) / 256, 256, 0, stream>>>(out, out_size, v);
    return;
  }
  const bool pathA16 = (ws_size >= needA16);

  wsum_k<<<2048, 256, 0, stream>>>(w1, w2, wpart);
  wfinal_k<<<1, 256, 0, stream>>>(wpart, swd, wsc);
  wquant_k<<<16384, 256, 0, stream>>>(w1, qw1, swd, 0);
  wquant_k<<<16384, 256, 0, stream>>>(w2, qw2, swd, 1);
  rmsq_k<<<N_TOK, 256, 0, stream>>>(x, gamma, qx, sxinv);

  const int nwg1 = (N_TOK / 128) * (D_HID / 128);  // 4096
  const int nwg2 = (N_TOK / 128) * (D_DIM / 128);  // 1024
  if (pathA16) {
    gemm4_i8_k<5><<<nwg1, 256, 0, stream>>>(qx, qw1, D_DIM, D_HID / 128, nullptr, h16,
                                            nullptr, D_HID, sxinv, wsc + 0, nullptr);
    hgeluq_k<<<N_TOK, 256, 0, stream>>>(h16, qh, shinv);
  } else {
    hipMemsetAsync(amaxh, 0, (size_t)N_TOK * 4, stream);
    gemm4_i8_k<0><<<nwg1, 256, 0, stream>>>(qx, qw1, D_DIM, D_HID / 128, nullptr, nullptr,
                                            nullptr, D_HID, sxinv, wsc + 0, amaxh);
    scalefix_k<<<(N_TOK + 255) / 256, 256, 0, stream>>>(amaxh, shinv);
    gemm4_i8_k<3><<<nwg1, 256, 0, stream>>>(qx, qw1, D_DIM, D_HID / 128, nullptr, nullptr,
                                            qh, D_HID, sxinv, wsc + 0, amaxh);
  }
  gemm4_i8_k<2><<<nwg2, 256, 0, stream>>>(qh, qw2, D_HID, D_DIM / 128, out, nullptr,
                                          nullptr, D_DIM, shinv, wsc + 1, nullptr);
}